// Round 5
// baseline (36.236 us; speedup 1.0000x reference)
//
#include <hip/hip_runtime.h>

// LocalDE: im2col patches (C=3,K=3 -> D=27) then all upper-triangular
// pairwise products (378) per position. Output [B*L, 378] fp32, 186 MB.
// Write-BW bound. R5: quasi-persistent blocks — 1922 blocks x 8 groups of
// 8 positions (96KB contiguous output per block). Pair table built once per
// block; patch staging double-buffered and software-pipelined (loads issued
// before compute, ds_write after). Plain float4 stores (nt regressed, R3/R4).

#define B_    32
#define C_    3
#define H_    64
#define W_    64
#define HOUT  62
#define WOUT  62
#define L_    (HOUT * WOUT)   // 3844
#define D_    27
#define NPAIR 378             // D*(D+1)/2
#define NQ4   189             // float4 words per 2 positions (756/4)
#define NPOS  (B_ * L_)       // 123008
#define NGRP  (NPOS / 8)      // 15376 groups of 8 positions
#define GPB   8               // groups per block
#define GRID  (NGRP / GPB)    // 1922 blocks

typedef float f32x4 __attribute__((ext_vector_type(4)));

__global__ __launch_bounds__(256) void localde_kernel(
    const float* __restrict__ x, float* __restrict__ out) {
  __shared__ unsigned int tab[NPAIR];   // pair -> (i | j<<8)
  __shared__ float pbuf[2][8][28];      // double-buffered: 8 positions x 27+pad

  const int tid  = threadIdx.x;
  const int lane = tid & 63;
  const int wv   = tid >> 6;

  // Pair-index table, once per block (amortized over 8 groups).
  for (int t = tid; t < NPAIR; t += 256) {
    int i = 0, s = 0;
    while (s + (D_ - i) <= t) { s += (D_ - i); ++i; }
    int j = i + (t - s);
    tab[t] = (unsigned)i | ((unsigned)j << 8);
  }

  // Staging-thread decode (tid < 216 stages one patch element).
  const int spos  = tid / D_;
  const int selem = tid - spos * D_;
  const int sc  = selem / 9;
  const int sr  = selem - sc * 9;
  const int ski = sr / 3;
  const int skj = sr - ski * 3;

  const int gbase = blockIdx.x * GPB;

  // Prologue: stage group 0 into buffer 0.
  if (tid < 8 * D_) {
    int gidx = gbase * 8 + spos;
    int b  = gidx / L_;
    int l  = gidx - b * L_;
    int oh = l / WOUT;
    int ow = l - oh * WOUT;
    pbuf[0][spos][selem] = x[((b * C_ + sc) * H_ + oh + ski) * W_ + ow + skj];
  }
  __syncthreads();

  for (int it = 0; it < GPB; ++it) {
    // Issue next group's loads EARLY (latency hides under the store phase).
    float staged = 0.0f;
    const bool do_stage = (tid < 8 * D_) && (it + 1 < GPB);
    if (do_stage) {
      int gidx = (gbase + it + 1) * 8 + spos;
      int b  = gidx / L_;
      int l  = gidx - b * L_;
      int oh = l / WOUT;
      int ow = l - oh * WOUT;
      staged = x[((b * C_ + sc) * H_ + oh + ski) * W_ + ow + skj];
    }

    // Compute: each wave emits 189 float4 covering 2 consecutive positions.
    const int g0 = (gbase + it) * 8 + wv * 2;
    f32x4* __restrict__ outp = (f32x4*)(out + (size_t)g0 * NPAIR);
    const float* __restrict__ pb = &pbuf[it & 1][wv * 2][0];
#pragma unroll
    for (int t = 0; t < 3; ++t) {
      int q = lane + t * 64;
      if (q < NQ4) {
        f32x4 v;
#pragma unroll
        for (int k = 0; k < 4; ++k) {
          int e  = 4 * q + k;
          int hi = (e >= NPAIR) ? 1 : 0;        // straddle into position g0+1
          int ee = e - hi * NPAIR;
          unsigned tw = tab[ee];
          const float* pp = pb + hi * 28;
          v[k] = pp[tw & 255u] * pp[(tw >> 8) & 255u];
        }
        outp[q] = v;
      }
    }

    // Write staged patch late, then one barrier per iteration.
    if (do_stage) pbuf[(it + 1) & 1][spos][selem] = staged;
    __syncthreads();
  }
}

extern "C" void kernel_launch(void* const* d_in, const int* in_sizes, int n_in,
                              void* d_out, int out_size, void* d_ws, size_t ws_size,
                              hipStream_t stream) {
  const float* x = (const float*)d_in[0];
  float* out = (float*)d_out;
  localde_kernel<<<GRID, 256, 0, stream>>>(x, out);
}